// Round 4
// baseline (1331.953 us; speedup 1.0000x reference)
//
#include <hip/hip_runtime.h>
#include <math.h>

// Problem constants
#define B_   64
#define C_   256
#define L_   1600          // H*W = 40*40
#define T_   25            // tokens per window (5x5)
#define ROWS (B_*L_)       // 102400
#define QSCALE 0.17677669529663687f   // 1/sqrt(32)

typedef _Float16 f16;
typedef f16 f16x8 __attribute__((ext_vector_type(8)));
typedef f16 f16x4 __attribute__((ext_vector_type(4)));
typedef f16 f16x2 __attribute__((ext_vector_type(2)));
typedef float f32x4 __attribute__((ext_vector_type(4)));

__device__ __forceinline__ void gload_lds16(const void* g, void* l) {
  __builtin_amdgcn_global_load_lds(
      (const __attribute__((address_space(1))) unsigned int*)g,
      (__attribute__((address_space(3))) unsigned int*)l, 16, 0, 0);
}

__device__ __forceinline__ float dot8(f16x8 a, f16x8 b, float acc) {
  union U { f16x8 v; f16x2 p[4]; };
  U ua; ua.v = a;
  U ub; ub.v = b;
#pragma unroll
  for (int i = 0; i < 4; ++i)
    acc = __builtin_amdgcn_fdot2(ua.p[i], ub.p[i], acc, false);
  return acc;
}

// ---------------------------------------------------------------------------
// Weight convert+transpose (tiled, coalesced): o(N,K) f16 = w(K,N)^T
__global__ __launch_bounds__(256) void wtrans(const float* __restrict__ w,
                                              f16* __restrict__ o, int K, int N) {
  __shared__ f16 tile[64][72];
  int tid = threadIdx.x;
  int n0 = blockIdx.x * 64, k0 = blockIdx.y * 64;
  int nn = tid & 63, kq = tid >> 6;
#pragma unroll
  for (int i = 0; i < 16; ++i) {
    int k = kq * 16 + i;
    tile[nn][k] = (f16)w[(size_t)(k0 + k) * N + n0 + nn];
  }
  __syncthreads();
#pragma unroll
  for (int jj = 0; jj < 2; ++jj) {
    int e = jj * 256 + tid;
    int nr = e >> 3, kb = e & 7;
    *(f16x8*)&o[(size_t)(n0 + nr) * K + k0 + kb * 8] = *(const f16x8*)&tile[nr][kb * 8];
  }
}

// ---------------------------------------------------------------------------
// LN1 fused (stats + apply + transpose): xs(ROWS,256) f16 from x(B,C,L), x read once
__global__ __launch_bounds__(256) void ln1_fused(const float* __restrict__ x,
    const float* __restrict__ g, const float* __restrict__ be,
    f16* __restrict__ xs) {
  __shared__ float t32[256][65];
  __shared__ float gL[256], beL[256];
  int tid = threadIdx.x;
  gL[tid] = g[tid]; beL[tid] = be[tid];
  int r0 = blockIdx.x * 64;
  int w = tid >> 6, rl = tid & 63;
  int grow = r0 + rl;
  int b = grow / L_, l = grow - b * L_;
  const float* xb = x + (size_t)b * (C_ * L_) + l;
#pragma unroll
  for (int i = 0; i < 64; ++i) {
    int c = w + i * 4;
    t32[c][rl] = xb[(size_t)c * L_];
  }
  __syncthreads();
  int row = tid >> 2, q = tid & 3;
  float s = 0.f, s2 = 0.f;
#pragma unroll
  for (int i = 0; i < 64; ++i) {
    float vv = t32[q * 64 + i][row];
    s += vv; s2 += vv * vv;
  }
  s += __shfl_xor(s, 1); s2 += __shfl_xor(s2, 1);
  s += __shfl_xor(s, 2); s2 += __shfl_xor(s2, 2);
  float m = s * (1.0f / 256.0f);
  float rr = rsqrtf(s2 * (1.0f / 256.0f) - m * m + 1e-5f);
  f16* orow = &xs[(size_t)(r0 + row) * 256 + q * 64];
#pragma unroll
  for (int z8 = 0; z8 < 8; ++z8) {
    f16x8 ov;
#pragma unroll
    for (int z = 0; z < 8; ++z) {
      int c = q * 64 + z8 * 8 + z;
      ov[z] = (f16)((t32[c][row] - m) * rr * gL[c] + beL[c]);
    }
    *(f16x8*)(orow + z8 * 8) = ov;
  }
}

// ---------------------------------------------------------------------------
// MFMA GEMM: C(M,N) = A(M,K)f16 @ BT(N,K)f16^T ; 128x128 tile, BK=32, 4 waves.
// EPI: 0 = +bias -> f16 out ; 1 = +bias -> f32 out ; 2 = gelu(+bias) -> f16 out
//      3 = +bias +resid -> transposed (B,512,L) f32 out
template<int K, int N, int EPI>
__global__ __launch_bounds__(256) void gemm16(
    const f16* __restrict__ A, const f16* __restrict__ BT,
    const float* __restrict__ bias, float* __restrict__ outF,
    f16* __restrict__ outH, const float* __restrict__ resid, int row_off) {
  __shared__ f16 As[128 * 32];
  __shared__ f16 Bs[128 * 32];
  __shared__ float tT[(EPI == 3) ? 64 * 129 : 1];
  int tid = threadIdx.x;
  int w = tid >> 6, lane = tid & 63;
  int wr = w >> 1, wc = w & 1;
  int r0 = blockIdx.x * 128;
  int n0 = blockIdx.y * 128;

  f32x4 acc[4][4] = {};

  for (int k0 = 0; k0 < K; k0 += 32) {
#pragma unroll
    for (int i = 0; i < 2; ++i) {
      int e = i * 256 + tid;
      int row = e >> 2, t = e & 3;
      int cb = t ^ ((row >> 1) & 3);
      gload_lds16(A + (size_t)(r0 + row) * K + k0 + cb * 8,
                  &As[(i * 4 + w) * 512]);
    }
#pragma unroll
    for (int i = 0; i < 2; ++i) {
      int e = i * 256 + tid;
      int row = e >> 2, t = e & 3;
      int cb = t ^ ((row >> 1) & 3);
      gload_lds16(BT + (size_t)(n0 + row) * K + k0 + cb * 8,
                  &Bs[(i * 4 + w) * 512]);
    }
    __syncthreads();

    f16x8 af[4], bf[4];
#pragma unroll
    for (int m = 0; m < 4; ++m) {
      int ar = wr * 64 + m * 16 + (lane & 15);
      int sl = (lane >> 4) ^ ((ar >> 1) & 3);
      af[m] = *(const f16x8*)&As[ar * 32 + sl * 8];
    }
#pragma unroll
    for (int n = 0; n < 4; ++n) {
      int br = wc * 64 + n * 16 + (lane & 15);
      int sl = (lane >> 4) ^ ((br >> 1) & 3);
      bf[n] = *(const f16x8*)&Bs[br * 32 + sl * 8];
    }
#pragma unroll
    for (int m = 0; m < 4; ++m)
#pragma unroll
      for (int n = 0; n < 4; ++n)
        acc[m][n] = __builtin_amdgcn_mfma_f32_16x16x32_f16(af[m], bf[n], acc[m][n], 0, 0, 0);
    __syncthreads();
  }

  if constexpr (EPI != 3) {
#pragma unroll
    for (int m = 0; m < 4; ++m) {
#pragma unroll
      for (int n = 0; n < 4; ++n) {
        int gcol = n0 + wc * 64 + n * 16 + (lane & 15);
        float bb = bias[gcol];
#pragma unroll
        for (int j = 0; j < 4; ++j) {
          int grow = r0 + wr * 64 + m * 16 + ((lane >> 4) << 2) + j;
          float v = acc[m][n][j] + bb;
          if constexpr (EPI == 0) {
            outH[(size_t)grow * N + gcol] = (f16)v;
          } else if constexpr (EPI == 1) {
            outF[(size_t)grow * N + gcol] = v;
          } else {
            float gl = 0.5f * v * (1.0f + erff(v * 0.70710678118654752f));
            outH[(size_t)grow * N + gcol] = (f16)gl;
          }
        }
      }
    }
  } else {
    for (int p = 0; p < 2; ++p) {
      if (wr == p) {
#pragma unroll
        for (int m = 0; m < 4; ++m) {
          int lr = m * 16 + ((lane >> 4) << 2);
#pragma unroll
          for (int n = 0; n < 4; ++n) {
            int lc = wc * 64 + n * 16 + (lane & 15);
            int gcol = n0 + lc;
            float bb = bias[gcol];
#pragma unroll
            for (int j = 0; j < 4; ++j) {
              int grow = row_off + r0 + p * 64 + lr + j;
              tT[(lr + j) * 129 + lc] =
                  acc[m][n][j] + bb + resid[(size_t)grow * 512 + gcol];
            }
          }
        }
      }
      __syncthreads();
#pragma unroll
      for (int it = 0; it < 8; ++it) {
        int idx = it * 256 + tid;
        int col = idx >> 4;
        int r4 = idx & 15;
        int grow0 = row_off + r0 + p * 64 + r4 * 4;
        int b = grow0 / L_;
        int l = grow0 - b * L_;
        float4 o = make_float4(tT[(r4 * 4 + 0) * 129 + col],
                               tT[(r4 * 4 + 1) * 129 + col],
                               tT[(r4 * 4 + 2) * 129 + col],
                               tT[(r4 * 4 + 3) * 129 + col]);
        *(float4*)&outF[((size_t)b * 512 + n0 + col) * L_ + l] = o;
      }
      __syncthreads();
    }
  }
}

// ---------------------------------------------------------------------------
// Window attention v3: one block per (b, window); scores+softmax+PV all in
// registers per (h,t) thread; K/V LDS reads are wave-broadcast. One barrier.
#define PST 776   // f16 per qc row: q|k|v each 256, stride 1552B (16B aligned)
__global__ __launch_bounds__(256, 4) void attn_kernel(const f16* __restrict__ qkv,
                                                      const float* __restrict__ rel,
                                                      f16* __restrict__ outp) {
  __shared__ f16 qc[T_][PST];     // 38800 B
  __shared__ f16 relL[81 * 8];    // 1296 B
  int tid = threadIdx.x;
  int bn = blockIdx.x;
  int b = bn >> 6, n = bn & 63;
  int u = n >> 3, v = n & 7;

  for (int e = tid; e < 648; e += 256) relL[e] = (f16)rel[e];

  // stage q,k,v: granule = f16x8 of 8 heads at one (t, which, d); permute to h*32+d
  for (int e = tid; e < T_ * 96; e += 256) {
    int t = e / 96;
    int g = e - t * 96;
    int i = t / 5, j = t - i * 5;
    int l = (u * 5 + i) * 40 + v * 5 + j;
    f16x8 val = *(const f16x8*)&qkv[(size_t)(b * L_ + l) * 768 + g * 8];
    int which = g >> 5;
    int d = g & 31;
    int base = which * 256 + d;
#pragma unroll
    for (int h = 0; h < 8; ++h)
      qc[t][base + h * 32] = val[h];
  }
  __syncthreads();

  int h = tid >> 5, t = tid & 31;
  if (t < T_) {
    int i1 = t / 5, j1 = t - i1 * 5;
    int par1 = (u + v + i1 + j1) & 1;
    const f16* qp = &qc[t][h * 32];
    f16x8 q0 = *(const f16x8*)(qp + 0);
    f16x8 q1 = *(const f16x8*)(qp + 8);
    f16x8 q2 = *(const f16x8*)(qp + 16);
    f16x8 q3 = *(const f16x8*)(qp + 24);

    float p[T_];
    float mx = -1e30f;
#pragma unroll
    for (int s = 0; s < T_; ++s) {
      int i2 = s / 5, j2 = s - i2 * 5;
      const f16* kp = &qc[s][256 + h * 32];
      f16x8 k0 = *(const f16x8*)(kp + 0);
      f16x8 k1 = *(const f16x8*)(kp + 8);
      f16x8 k2 = *(const f16x8*)(kp + 16);
      f16x8 k3 = *(const f16x8*)(kp + 24);
      float d0 = 0.f, d1 = 0.f;
      d0 = dot8(q0, k0, d0);
      d1 = dot8(q1, k1, d1);
      d0 = dot8(q2, k2, d0);
      d1 = dot8(q3, k3, d1);
      float bias = (float)relL[((i1 - i2 + 4) * 9 + (j1 - j2 + 4)) * 8 + h];
      int par2 = (u + v + i2 + j2) & 1;
      float sc = (d0 + d1) * QSCALE + bias + ((par1 & par2) ? 0.0f : -100.0f);
      p[s] = sc;
      mx = fmaxf(mx, sc);
    }
    float sum = 0.f;
#pragma unroll
    for (int s = 0; s < T_; ++s) {
      float e = __expf(p[s] - mx);
      p[s] = e;
      sum += e;
    }
    float inv = 1.0f / sum;
#pragma unroll
    for (int s = 0; s < T_; ++s) p[s] *= inv;

    // PV: 32 f32 accumulators, V rows broadcast from LDS
    float acc[32] = {};
#pragma unroll
    for (int s = 0; s < T_; ++s) {
      const f16* vp = &qc[s][512 + h * 32];
      f16x8 v0 = *(const f16x8*)(vp + 0);
      f16x8 v1 = *(const f16x8*)(vp + 8);
      f16x8 v2 = *(const f16x8*)(vp + 16);
      f16x8 v3 = *(const f16x8*)(vp + 24);
      float ps = p[s];
#pragma unroll
      for (int z = 0; z < 8; ++z) {
        acc[z]      += ps * (float)v0[z];
        acc[8 + z]  += ps * (float)v1[z];
        acc[16 + z] += ps * (float)v2[z];
        acc[24 + z] += ps * (float)v3[z];
      }
    }
    int l = (u * 5 + i1) * 40 + v * 5 + j1;
    f16* op = &outp[(size_t)(b * L_ + l) * 256 + h * 32];
#pragma unroll
    for (int z4 = 0; z4 < 4; ++z4) {
      f16x8 ov;
#pragma unroll
      for (int z = 0; z < 8; ++z) ov[z] = (f16)acc[z4 * 8 + z];
      *(f16x8*)(op + z4 * 8) = ov;
    }
  }
}

// ---------------------------------------------------------------------------
// LN2 fused (stats + apply): yln(ROWS,512) f16 = LN(y)*g+b, y read once
__global__ __launch_bounds__(256) void ln2_fused(const float* __restrict__ y,
    const float* __restrict__ g, const float* __restrict__ be,
    f16* __restrict__ yln) {
  int wv = threadIdx.x >> 6, lane = threadIdx.x & 63;
  int row = blockIdx.x * 4 + wv;
  const float4* yp = (const float4*)(y + (size_t)row * 512);
  float4 v0 = yp[lane];
  float4 v1 = yp[lane + 64];
  float s = v0.x + v0.y + v0.z + v0.w + v1.x + v1.y + v1.z + v1.w;
  float s2 = v0.x * v0.x + v0.y * v0.y + v0.z * v0.z + v0.w * v0.w
           + v1.x * v1.x + v1.y * v1.y + v1.z * v1.z + v1.w * v1.w;
#pragma unroll
  for (int o = 32; o; o >>= 1) { s += __shfl_xor(s, o); s2 += __shfl_xor(s2, o); }
  float m = s * (1.0f / 512.0f);
  float rr = rsqrtf(s2 * (1.0f / 512.0f) - m * m + 1e-5f);
  float4 g0 = ((const float4*)g)[lane], g1 = ((const float4*)g)[lane + 64];
  float4 b0 = ((const float4*)be)[lane], b1 = ((const float4*)be)[lane + 64];
  f16x4 o0, o1;
  o0[0] = (f16)((v0.x - m) * rr * g0.x + b0.x);
  o0[1] = (f16)((v0.y - m) * rr * g0.y + b0.y);
  o0[2] = (f16)((v0.z - m) * rr * g0.z + b0.z);
  o0[3] = (f16)((v0.w - m) * rr * g0.w + b0.w);
  o1[0] = (f16)((v1.x - m) * rr * g1.x + b1.x);
  o1[1] = (f16)((v1.y - m) * rr * g1.y + b1.y);
  o1[2] = (f16)((v1.z - m) * rr * g1.z + b1.z);
  o1[3] = (f16)((v1.w - m) * rr * g1.w + b1.w);
  f16* orow = &yln[(size_t)row * 512];
  *(f16x4*)(orow + lane * 4) = o0;
  *(f16x4*)(orow + 256 + lane * 4) = o1;
}

// ---------------------------------------------------------------------------
extern "C" void kernel_launch(void* const* d_in, const int* in_sizes, int n_in,
                              void* d_out, int out_size, void* d_ws, size_t ws_size,
                              hipStream_t stream) {
  const float* x      = (const float*)d_in[0];
  const float* qkv_w  = (const float*)d_in[1];
  const float* qkv_b  = (const float*)d_in[2];
  const float* rel    = (const float*)d_in[3];
  const float* proj_w = (const float*)d_in[4];
  const float* proj_b = (const float*)d_in[5];
  const float* w1     = (const float*)d_in[6];
  const float* b1     = (const float*)d_in[7];
  const float* w2     = (const float*)d_in[8];
  const float* b2     = (const float*)d_in[9];
  const float* g1     = (const float*)d_in[10];
  const float* be1    = (const float*)d_in[11];
  const float* g2     = (const float*)d_in[12];
  const float* be2    = (const float*)d_in[13];
  float* out = (float*)d_out;

  // ws layout (bytes):
  //   0        : (reserved stats region, unused now) 1,638,400
  //   1638400  : f16 weights qkv_wT, proj_wT, w1T, w2T
  //   4390912  : P0 (210MB): qkv_h f16 -> later y f32
  //   +P0      : P1 (105MB): xs_h | att_h -> later yln f16
  //   +P1      : P2: hid f16 (full 210MB if ws allows, else 52.4MB chunk)
  char* w8 = (char*)d_ws;
  f16* qkv_wT  = (f16*)(w8 + 1638400);
  f16* proj_wT = qkv_wT + 768 * 256;
  f16* w1T     = proj_wT + 512 * 256;
  f16* w2T     = w1T + 1024 * 512;
  char* P0 = w8 + 4390912;
  f16*   qkv_h = (f16*)P0;
  float* y     = (float*)P0;
  char* P1 = P0 + (size_t)ROWS * 512 * 4;
  f16* xs_h  = (f16*)P1;
  f16* att_h = (f16*)(P1 + (size_t)ROWS * 256 * 2);
  f16* yln   = (f16*)P1;
  char* P2 = P1 + (size_t)ROWS * 512 * 2;
  f16* hid = (f16*)P2;

  size_t need_full = 4390912 + (size_t)ROWS * 512 * 4 + (size_t)ROWS * 512 * 2
                   + (size_t)ROWS * 1024 * 2;
  bool full = ws_size >= need_full;

  wtrans<<<dim3(768 / 64, 256 / 64), 256, 0, stream>>>(qkv_w, qkv_wT, 256, 768);
  wtrans<<<dim3(512 / 64, 256 / 64), 256, 0, stream>>>(proj_w, proj_wT, 256, 512);
  wtrans<<<dim3(1024 / 64, 512 / 64), 256, 0, stream>>>(w1, w1T, 512, 1024);
  wtrans<<<dim3(512 / 64, 1024 / 64), 256, 0, stream>>>(w2, w2T, 1024, 512);

  ln1_fused<<<ROWS / 64, 256, 0, stream>>>(x, g1, be1, xs_h);

  gemm16<256, 768, 0><<<dim3(ROWS / 128, 6), 256, 0, stream>>>(
      xs_h, qkv_wT, qkv_b, nullptr, qkv_h, nullptr, 0);

  attn_kernel<<<B_ * 64, 256, 0, stream>>>(qkv_h, rel, att_h);

  gemm16<256, 512, 1><<<dim3(ROWS / 128, 4), 256, 0, stream>>>(
      att_h, proj_wT, proj_b, y, nullptr, nullptr, 0);

  ln2_fused<<<ROWS / 4, 256, 0, stream>>>(y, g2, be2, yln);

  if (full) {
    gemm16<512, 1024, 2><<<dim3(ROWS / 128, 8), 256, 0, stream>>>(
        yln, w1T, b1, nullptr, hid, nullptr, 0);
    gemm16<1024, 512, 3><<<dim3(ROWS / 128, 4), 256, 0, stream>>>(
        hid, w2T, b2, out, nullptr, y, 0);
  } else {
    const int CHUNK = ROWS / 4;  // 25600 rows
    for (int c = 0; c < 4; ++c) {
      int off = c * CHUNK;
      gemm16<512, 1024, 2><<<dim3(CHUNK / 128, 8), 256, 0, stream>>>(
          yln + (size_t)off * 512, w1T, b1, nullptr, hid, nullptr, 0);
      gemm16<1024, 512, 3><<<dim3(CHUNK / 128, 4), 256, 0, stream>>>(
          hid, w2T, b2, out, nullptr, y, off);
    }
  }
  (void)in_sizes; (void)n_in; (void)out_size;
}

// Round 5
// 831.622 us; speedup vs baseline: 1.6016x; 1.6016x over previous
//
#include <hip/hip_runtime.h>
#include <math.h>

// Problem constants
#define B_   64
#define C_   256
#define L_   1600          // H*W = 40*40
#define T_   25            // tokens per window (5x5)
#define ROWS (B_*L_)       // 102400
#define QSCALE 0.17677669529663687f   // 1/sqrt(32)

typedef _Float16 f16;
typedef f16 f16x8 __attribute__((ext_vector_type(8)));
typedef f16 f16x4 __attribute__((ext_vector_type(4)));
typedef f16 f16x2 __attribute__((ext_vector_type(2)));
typedef float f32x4 __attribute__((ext_vector_type(4)));

__device__ __forceinline__ void gload_lds16(const void* g, void* l) {
  __builtin_amdgcn_global_load_lds(
      (const __attribute__((address_space(1))) unsigned int*)g,
      (__attribute__((address_space(3))) unsigned int*)l, 16, 0, 0);
}

__device__ __forceinline__ float dot8(f16x8 a, f16x8 b, float acc) {
  union U { f16x8 v; f16x2 p[4]; };
  U ua; ua.v = a;
  U ub; ub.v = b;
#pragma unroll
  for (int i = 0; i < 4; ++i)
    acc = __builtin_amdgcn_fdot2(ua.p[i], ub.p[i], acc, false);
  return acc;
}

// ---------------------------------------------------------------------------
// Weight convert+transpose (tiled, coalesced): o(N,K) f16 = w(K,N)^T
__global__ __launch_bounds__(256) void wtrans(const float* __restrict__ w,
                                              f16* __restrict__ o, int K, int N) {
  __shared__ f16 tile[64][72];
  int tid = threadIdx.x;
  int n0 = blockIdx.x * 64, k0 = blockIdx.y * 64;
  int nn = tid & 63, kq = tid >> 6;
#pragma unroll
  for (int i = 0; i < 16; ++i) {
    int k = kq * 16 + i;
    tile[nn][k] = (f16)w[(size_t)(k0 + k) * N + n0 + nn];
  }
  __syncthreads();
#pragma unroll
  for (int jj = 0; jj < 2; ++jj) {
    int e = jj * 256 + tid;
    int nr = e >> 3, kb = e & 7;
    *(f16x8*)&o[(size_t)(n0 + nr) * K + k0 + kb * 8] = *(const f16x8*)&tile[nr][kb * 8];
  }
}

// ---------------------------------------------------------------------------
// LN1 fused (stats + apply + transpose): xs(ROWS,256) f16 from x(B,C,L), x read once
__global__ __launch_bounds__(256) void ln1_fused(const float* __restrict__ x,
    const float* __restrict__ g, const float* __restrict__ be,
    f16* __restrict__ xs) {
  __shared__ float t32[256][65];
  __shared__ float gL[256], beL[256];
  int tid = threadIdx.x;
  gL[tid] = g[tid]; beL[tid] = be[tid];
  int r0 = blockIdx.x * 64;
  int w = tid >> 6, rl = tid & 63;
  int grow = r0 + rl;
  int b = grow / L_, l = grow - b * L_;
  const float* xb = x + (size_t)b * (C_ * L_) + l;
#pragma unroll
  for (int i = 0; i < 64; ++i) {
    int c = w + i * 4;
    t32[c][rl] = xb[(size_t)c * L_];
  }
  __syncthreads();
  int row = tid >> 2, q = tid & 3;
  float s = 0.f, s2 = 0.f;
#pragma unroll
  for (int i = 0; i < 64; ++i) {
    float vv = t32[q * 64 + i][row];
    s += vv; s2 += vv * vv;
  }
  s += __shfl_xor(s, 1); s2 += __shfl_xor(s2, 1);
  s += __shfl_xor(s, 2); s2 += __shfl_xor(s2, 2);
  float m = s * (1.0f / 256.0f);
  float rr = rsqrtf(s2 * (1.0f / 256.0f) - m * m + 1e-5f);
  f16* orow = &xs[(size_t)(r0 + row) * 256 + q * 64];
#pragma unroll
  for (int z8 = 0; z8 < 8; ++z8) {
    f16x8 ov;
#pragma unroll
    for (int z = 0; z < 8; ++z) {
      int c = q * 64 + z8 * 8 + z;
      ov[z] = (f16)((t32[c][row] - m) * rr * gL[c] + beL[c]);
    }
    *(f16x8*)(orow + z8 * 8) = ov;
  }
}

// ---------------------------------------------------------------------------
// MFMA GEMM: C(M,N) = A(M,K)f16 @ BT(N,K)f16^T ; 128x128 tile, BK=32, 4 waves.
// EPI: 0 = +bias -> f16 out ; 1 = +bias -> f32 out ; 2 = gelu(+bias) -> f16 out
//      3 = +bias +resid -> transposed (B,512,L) f32 out
template<int K, int N, int EPI>
__global__ __launch_bounds__(256) void gemm16(
    const f16* __restrict__ A, const f16* __restrict__ BT,
    const float* __restrict__ bias, float* __restrict__ outF,
    f16* __restrict__ outH, const float* __restrict__ resid, int row_off) {
  __shared__ f16 As[128 * 32];
  __shared__ f16 Bs[128 * 32];
  __shared__ float tT[(EPI == 3) ? 64 * 129 : 1];
  int tid = threadIdx.x;
  int w = tid >> 6, lane = tid & 63;
  int wr = w >> 1, wc = w & 1;
  int r0 = blockIdx.x * 128;
  int n0 = blockIdx.y * 128;

  f32x4 acc[4][4] = {};

  for (int k0 = 0; k0 < K; k0 += 32) {
#pragma unroll
    for (int i = 0; i < 2; ++i) {
      int e = i * 256 + tid;
      int row = e >> 2, t = e & 3;
      int cb = t ^ ((row >> 1) & 3);
      gload_lds16(A + (size_t)(r0 + row) * K + k0 + cb * 8,
                  &As[(i * 4 + w) * 512]);
    }
#pragma unroll
    for (int i = 0; i < 2; ++i) {
      int e = i * 256 + tid;
      int row = e >> 2, t = e & 3;
      int cb = t ^ ((row >> 1) & 3);
      gload_lds16(BT + (size_t)(n0 + row) * K + k0 + cb * 8,
                  &Bs[(i * 4 + w) * 512]);
    }
    __syncthreads();

    f16x8 af[4], bf[4];
#pragma unroll
    for (int m = 0; m < 4; ++m) {
      int ar = wr * 64 + m * 16 + (lane & 15);
      int sl = (lane >> 4) ^ ((ar >> 1) & 3);
      af[m] = *(const f16x8*)&As[ar * 32 + sl * 8];
    }
#pragma unroll
    for (int n = 0; n < 4; ++n) {
      int br = wc * 64 + n * 16 + (lane & 15);
      int sl = (lane >> 4) ^ ((br >> 1) & 3);
      bf[n] = *(const f16x8*)&Bs[br * 32 + sl * 8];
    }
#pragma unroll
    for (int m = 0; m < 4; ++m)
#pragma unroll
      for (int n = 0; n < 4; ++n)
        acc[m][n] = __builtin_amdgcn_mfma_f32_16x16x32_f16(af[m], bf[n], acc[m][n], 0, 0, 0);
    __syncthreads();
  }

  if constexpr (EPI != 3) {
#pragma unroll
    for (int m = 0; m < 4; ++m) {
#pragma unroll
      for (int n = 0; n < 4; ++n) {
        int gcol = n0 + wc * 64 + n * 16 + (lane & 15);
        float bb = bias[gcol];
#pragma unroll
        for (int j = 0; j < 4; ++j) {
          int grow = r0 + wr * 64 + m * 16 + ((lane >> 4) << 2) + j;
          float v = acc[m][n][j] + bb;
          if constexpr (EPI == 0) {
            outH[(size_t)grow * N + gcol] = (f16)v;
          } else if constexpr (EPI == 1) {
            outF[(size_t)grow * N + gcol] = v;
          } else {
            float gl = 0.5f * v * (1.0f + erff(v * 0.70710678118654752f));
            outH[(size_t)grow * N + gcol] = (f16)gl;
          }
        }
      }
    }
  } else {
    for (int p = 0; p < 2; ++p) {
      if (wr == p) {
#pragma unroll
        for (int m = 0; m < 4; ++m) {
          int lr = m * 16 + ((lane >> 4) << 2);
#pragma unroll
          for (int n = 0; n < 4; ++n) {
            int lc = wc * 64 + n * 16 + (lane & 15);
            int gcol = n0 + lc;
            float bb = bias[gcol];
#pragma unroll
            for (int j = 0; j < 4; ++j) {
              int grow = row_off + r0 + p * 64 + lr + j;
              tT[(lr + j) * 129 + lc] =
                  acc[m][n][j] + bb + resid[(size_t)grow * 512 + gcol];
            }
          }
        }
      }
      __syncthreads();
#pragma unroll
      for (int it = 0; it < 8; ++it) {
        int idx = it * 256 + tid;
        int col = idx >> 4;
        int r4 = idx & 15;
        int grow0 = row_off + r0 + p * 64 + r4 * 4;
        int b = grow0 / L_;
        int l = grow0 - b * L_;
        float4 o = make_float4(tT[(r4 * 4 + 0) * 129 + col],
                               tT[(r4 * 4 + 1) * 129 + col],
                               tT[(r4 * 4 + 2) * 129 + col],
                               tT[(r4 * 4 + 3) * 129 + col]);
        *(float4*)&outF[((size_t)b * 512 + n0 + col) * L_ + l] = o;
      }
      __syncthreads();
    }
  }
}

// ---------------------------------------------------------------------------
// Window attention v3b: one block per (b, window); scores+softmax in registers
// per (h,t) thread; PV in two 16-wide halves to bound VGPR pressure (<128).
// NO min-waves clamp (round-4 regression: __launch_bounds__(256,4) -> 64 VGPR
// cap -> p[]/acc[] spilled to scratch -> 2 GB HBM spill traffic per dispatch).
#define PST 776   // f16 per qc row: q|k|v each 256, stride 1552B (16B aligned)
__global__ __launch_bounds__(256) void attn_kernel(const f16* __restrict__ qkv,
                                                   const float* __restrict__ rel,
                                                   f16* __restrict__ outp) {
  __shared__ f16 qc[T_][PST];     // 38800 B
  __shared__ f16 relL[81 * 8];    // 1296 B
  int tid = threadIdx.x;
  int bn = blockIdx.x;
  int b = bn >> 6, n = bn & 63;
  int u = n >> 3, v = n & 7;

  for (int e = tid; e < 648; e += 256) relL[e] = (f16)rel[e];

  // stage q,k,v: granule = f16x8 of 8 heads at one (t, which, d); permute to h*32+d
  for (int e = tid; e < T_ * 96; e += 256) {
    int t = e / 96;
    int g = e - t * 96;
    int i = t / 5, j = t - i * 5;
    int l = (u * 5 + i) * 40 + v * 5 + j;
    f16x8 val = *(const f16x8*)&qkv[(size_t)(b * L_ + l) * 768 + g * 8];
    int which = g >> 5;
    int d = g & 31;
    int base = which * 256 + d;
#pragma unroll
    for (int h = 0; h < 8; ++h)
      qc[t][base + h * 32] = val[h];
  }
  __syncthreads();

  int h = tid >> 5, t = tid & 31;
  if (t < T_) {
    int i1 = t / 5, j1 = t - i1 * 5;
    int par1 = (u + v + i1 + j1) & 1;
    const f16* qp = &qc[t][h * 32];
    f16x8 q0 = *(const f16x8*)(qp + 0);
    f16x8 q1 = *(const f16x8*)(qp + 8);
    f16x8 q2 = *(const f16x8*)(qp + 16);
    f16x8 q3 = *(const f16x8*)(qp + 24);

    float p[T_];
    float mx = -1e30f;
#pragma unroll
    for (int s = 0; s < T_; ++s) {
      int i2 = s / 5, j2 = s - i2 * 5;
      const f16* kp = &qc[s][256 + h * 32];
      f16x8 k0 = *(const f16x8*)(kp + 0);
      f16x8 k1 = *(const f16x8*)(kp + 8);
      f16x8 k2 = *(const f16x8*)(kp + 16);
      f16x8 k3 = *(const f16x8*)(kp + 24);
      float d0 = 0.f, d1 = 0.f;
      d0 = dot8(q0, k0, d0);
      d1 = dot8(q1, k1, d1);
      d0 = dot8(q2, k2, d0);
      d1 = dot8(q3, k3, d1);
      float bias = (float)relL[((i1 - i2 + 4) * 9 + (j1 - j2 + 4)) * 8 + h];
      int par2 = (u + v + i2 + j2) & 1;
      float sc = (d0 + d1) * QSCALE + bias + ((par1 & par2) ? 0.0f : -100.0f);
      p[s] = sc;
      mx = fmaxf(mx, sc);
    }
    float sum = 0.f;
#pragma unroll
    for (int s = 0; s < T_; ++s) {
      float e = __expf(p[s] - mx);
      p[s] = e;
      sum += e;
    }
    float inv = 1.0f / sum;
#pragma unroll
    for (int s = 0; s < T_; ++s) p[s] *= inv;

    int l = (u * 5 + i1) * 40 + v * 5 + j1;
    f16* op = &outp[(size_t)(b * L_ + l) * 256 + h * 32];

    // PV in two halves of 16 output dims each (bounds peak VGPR pressure)
#pragma unroll
    for (int half = 0; half < 2; ++half) {
      float acc[16] = {};
#pragma unroll
      for (int s = 0; s < T_; ++s) {
        const f16* vp = &qc[s][512 + h * 32 + half * 16];
        f16x8 v0 = *(const f16x8*)(vp + 0);
        f16x8 v1 = *(const f16x8*)(vp + 8);
        float ps = p[s];
#pragma unroll
        for (int z = 0; z < 8; ++z) {
          acc[z]     += ps * (float)v0[z];
          acc[8 + z] += ps * (float)v1[z];
        }
      }
#pragma unroll
      for (int z8 = 0; z8 < 2; ++z8) {
        f16x8 ov;
#pragma unroll
        for (int z = 0; z < 8; ++z) ov[z] = (f16)acc[z8 * 8 + z];
        *(f16x8*)(op + half * 16 + z8 * 8) = ov;
      }
    }
  }
}

// ---------------------------------------------------------------------------
// LN2 fused (stats + apply): yln(ROWS,512) f16 = LN(y)*g+b, y read once
__global__ __launch_bounds__(256) void ln2_fused(const float* __restrict__ y,
    const float* __restrict__ g, const float* __restrict__ be,
    f16* __restrict__ yln) {
  int wv = threadIdx.x >> 6, lane = threadIdx.x & 63;
  int row = blockIdx.x * 4 + wv;
  const float4* yp = (const float4*)(y + (size_t)row * 512);
  float4 v0 = yp[lane];
  float4 v1 = yp[lane + 64];
  float s = v0.x + v0.y + v0.z + v0.w + v1.x + v1.y + v1.z + v1.w;
  float s2 = v0.x * v0.x + v0.y * v0.y + v0.z * v0.z + v0.w * v0.w
           + v1.x * v1.x + v1.y * v1.y + v1.z * v1.z + v1.w * v1.w;
#pragma unroll
  for (int o = 32; o; o >>= 1) { s += __shfl_xor(s, o); s2 += __shfl_xor(s2, o); }
  float m = s * (1.0f / 512.0f);
  float rr = rsqrtf(s2 * (1.0f / 512.0f) - m * m + 1e-5f);
  float4 g0 = ((const float4*)g)[lane], g1 = ((const float4*)g)[lane + 64];
  float4 b0 = ((const float4*)be)[lane], b1 = ((const float4*)be)[lane + 64];
  f16x4 o0, o1;
  o0[0] = (f16)((v0.x - m) * rr * g0.x + b0.x);
  o0[1] = (f16)((v0.y - m) * rr * g0.y + b0.y);
  o0[2] = (f16)((v0.z - m) * rr * g0.z + b0.z);
  o0[3] = (f16)((v0.w - m) * rr * g0.w + b0.w);
  o1[0] = (f16)((v1.x - m) * rr * g1.x + b1.x);
  o1[1] = (f16)((v1.y - m) * rr * g1.y + b1.y);
  o1[2] = (f16)((v1.z - m) * rr * g1.z + b1.z);
  o1[3] = (f16)((v1.w - m) * rr * g1.w + b1.w);
  f16* orow = &yln[(size_t)row * 512];
  *(f16x4*)(orow + lane * 4) = o0;
  *(f16x4*)(orow + 256 + lane * 4) = o1;
}

// ---------------------------------------------------------------------------
extern "C" void kernel_launch(void* const* d_in, const int* in_sizes, int n_in,
                              void* d_out, int out_size, void* d_ws, size_t ws_size,
                              hipStream_t stream) {
  const float* x      = (const float*)d_in[0];
  const float* qkv_w  = (const float*)d_in[1];
  const float* qkv_b  = (const float*)d_in[2];
  const float* rel    = (const float*)d_in[3];
  const float* proj_w = (const float*)d_in[4];
  const float* proj_b = (const float*)d_in[5];
  const float* w1     = (const float*)d_in[6];
  const float* b1     = (const float*)d_in[7];
  const float* w2     = (const float*)d_in[8];
  const float* b2     = (const float*)d_in[9];
  const float* g1     = (const float*)d_in[10];
  const float* be1    = (const float*)d_in[11];
  const float* g2     = (const float*)d_in[12];
  const float* be2    = (const float*)d_in[13];
  float* out = (float*)d_out;

  // ws layout (bytes):
  //   0        : (reserved) 1,638,400
  //   1638400  : f16 weights qkv_wT, proj_wT, w1T, w2T
  //   4390912  : P0 (210MB): qkv_h f16 -> later y f32
  //   +P0      : P1 (105MB): xs_h | att_h -> later yln f16
  //   +P1      : P2: hid f16 (full 210MB if ws allows, else 52.4MB chunk)
  char* w8 = (char*)d_ws;
  f16* qkv_wT  = (f16*)(w8 + 1638400);
  f16* proj_wT = qkv_wT + 768 * 256;
  f16* w1T     = proj_wT + 512 * 256;
  f16* w2T     = w1T + 1024 * 512;
  char* P0 = w8 + 4390912;
  f16*   qkv_h = (f16*)P0;
  float* y     = (float*)P0;
  char* P1 = P0 + (size_t)ROWS * 512 * 4;
  f16* xs_h  = (f16*)P1;
  f16* att_h = (f16*)(P1 + (size_t)ROWS * 256 * 2);
  f16* yln   = (f16*)P1;
  char* P2 = P1 + (size_t)ROWS * 512 * 2;
  f16* hid = (f16*)P2;

  size_t need_full = 4390912 + (size_t)ROWS * 512 * 4 + (size_t)ROWS * 512 * 2
                   + (size_t)ROWS * 1024 * 2;
  bool full = ws_size >= need_full;

  wtrans<<<dim3(768 / 64, 256 / 64), 256, 0, stream>>>(qkv_w, qkv_wT, 256, 768);
  wtrans<<<dim3(512 / 64, 256 / 64), 256, 0, stream>>>(proj_w, proj_wT, 256, 512);
  wtrans<<<dim3(1024 / 64, 512 / 64), 256, 0, stream>>>(w1, w1T, 512, 1024);
  wtrans<<<dim3(512 / 64, 1024 / 64), 256, 0, stream>>>(w2, w2T, 1024, 512);

  ln1_fused<<<ROWS / 64, 256, 0, stream>>>(x, g1, be1, xs_h);

  gemm16<256, 768, 0><<<dim3(ROWS / 128, 6), 256, 0, stream>>>(
      xs_h, qkv_wT, qkv_b, nullptr, qkv_h, nullptr, 0);

  attn_kernel<<<B_ * 64, 256, 0, stream>>>(qkv_h, rel, att_h);

  gemm16<256, 512, 1><<<dim3(ROWS / 128, 4), 256, 0, stream>>>(
      att_h, proj_wT, proj_b, y, nullptr, nullptr, 0);

  ln2_fused<<<ROWS / 4, 256, 0, stream>>>(y, g2, be2, yln);

  if (full) {
    gemm16<512, 1024, 2><<<dim3(ROWS / 128, 8), 256, 0, stream>>>(
        yln, w1T, b1, nullptr, hid, nullptr, 0);
    gemm16<1024, 512, 3><<<dim3(ROWS / 128, 4), 256, 0, stream>>>(
        hid, w2T, b2, out, nullptr, y, 0);
  } else {
    const int CHUNK = ROWS / 4;  // 25600 rows
    for (int c = 0; c < 4; ++c) {
      int off = c * CHUNK;
      gemm16<512, 1024, 2><<<dim3(CHUNK / 128, 8), 256, 0, stream>>>(
          yln + (size_t)off * 512, w1T, b1, nullptr, hid, nullptr, 0);
      gemm16<1024, 512, 3><<<dim3(CHUNK / 128, 4), 256, 0, stream>>>(
          hid, w2T, b2, out, nullptr, y, off);
    }
  }
  (void)in_sizes; (void)n_in; (void)out_size;
}

// Round 6
// 783.051 us; speedup vs baseline: 1.7010x; 1.0620x over previous
//
#include <hip/hip_runtime.h>
#include <math.h>

// Problem constants
#define B_   64
#define C_   256
#define L_   1600          // H*W = 40*40
#define T_   25            // tokens per window (5x5)
#define ROWS (B_*L_)       // 102400
#define QSCALE 0.17677669529663687f   // 1/sqrt(32)

typedef _Float16 f16;
typedef f16 f16x8 __attribute__((ext_vector_type(8)));
typedef f16 f16x4 __attribute__((ext_vector_type(4)));
typedef f16 f16x2 __attribute__((ext_vector_type(2)));
typedef float f32x4 __attribute__((ext_vector_type(4)));

__device__ __forceinline__ void gload_lds16(const void* g, void* l) {
  __builtin_amdgcn_global_load_lds(
      (const __attribute__((address_space(1))) unsigned int*)g,
      (__attribute__((address_space(3))) unsigned int*)l, 16, 0, 0);
}

__device__ __forceinline__ float dot8(f16x8 a, f16x8 b, float acc) {
  union U { f16x8 v; f16x2 p[4]; };
  U ua; ua.v = a;
  U ub; ub.v = b;
#pragma unroll
  for (int i = 0; i < 4; ++i)
    acc = __builtin_amdgcn_fdot2(ua.p[i], ub.p[i], acc, false);
  return acc;
}

// ---------------------------------------------------------------------------
// Weight convert+transpose (tiled, coalesced): o(N,K) f16 = w(K,N)^T
__global__ __launch_bounds__(256) void wtrans(const float* __restrict__ w,
                                              f16* __restrict__ o, int K, int N) {
  __shared__ f16 tile[64][72];
  int tid = threadIdx.x;
  int n0 = blockIdx.x * 64, k0 = blockIdx.y * 64;
  int nn = tid & 63, kq = tid >> 6;
#pragma unroll
  for (int i = 0; i < 16; ++i) {
    int k = kq * 16 + i;
    tile[nn][k] = (f16)w[(size_t)(k0 + k) * N + n0 + nn];
  }
  __syncthreads();
#pragma unroll
  for (int jj = 0; jj < 2; ++jj) {
    int e = jj * 256 + tid;
    int nr = e >> 3, kb = e & 7;
    *(f16x8*)&o[(size_t)(n0 + nr) * K + k0 + kb * 8] = *(const f16x8*)&tile[nr][kb * 8];
  }
}

// ---------------------------------------------------------------------------
// LN1 fused (stats + apply + transpose): xs(ROWS,256) f16 from x(B,C,L), x read once
__global__ __launch_bounds__(256) void ln1_fused(const float* __restrict__ x,
    const float* __restrict__ g, const float* __restrict__ be,
    f16* __restrict__ xs) {
  __shared__ float t32[256][65];
  __shared__ float gL[256], beL[256];
  int tid = threadIdx.x;
  gL[tid] = g[tid]; beL[tid] = be[tid];
  int r0 = blockIdx.x * 64;
  int w = tid >> 6, rl = tid & 63;
  int grow = r0 + rl;
  int b = grow / L_, l = grow - b * L_;
  const float* xb = x + (size_t)b * (C_ * L_) + l;
#pragma unroll
  for (int i = 0; i < 64; ++i) {
    int c = w + i * 4;
    t32[c][rl] = xb[(size_t)c * L_];
  }
  __syncthreads();
  int row = tid >> 2, q = tid & 3;
  float s = 0.f, s2 = 0.f;
#pragma unroll
  for (int i = 0; i < 64; ++i) {
    float vv = t32[q * 64 + i][row];
    s += vv; s2 += vv * vv;
  }
  s += __shfl_xor(s, 1); s2 += __shfl_xor(s2, 1);
  s += __shfl_xor(s, 2); s2 += __shfl_xor(s2, 2);
  float m = s * (1.0f / 256.0f);
  float rr = rsqrtf(s2 * (1.0f / 256.0f) - m * m + 1e-5f);
  f16* orow = &xs[(size_t)(r0 + row) * 256 + q * 64];
#pragma unroll
  for (int z8 = 0; z8 < 8; ++z8) {
    f16x8 ov;
#pragma unroll
    for (int z = 0; z < 8; ++z) {
      int c = q * 64 + z8 * 8 + z;
      ov[z] = (f16)((t32[c][row] - m) * rr * gL[c] + beL[c]);
    }
    *(f16x8*)(orow + z8 * 8) = ov;
  }
}

// ---------------------------------------------------------------------------
// MFMA GEMM: C(M,N) = A(M,K)f16 @ BT(N,K)f16^T ; 128x128 tile, BK=32, 4 waves.
// Grid: blockIdx.x = COLUMN block (fast dim -> concurrent A-panel sharing via L3),
//       blockIdx.y = row block.
// EPI: 0 = +bias -> f16 out ; 2 = gelu(+bias) -> f16 out
//      3 = +bias +resid(f16) -> transposed (B,512,L) f32 out
// EPI=3 aliases tT over As/Bs (live ranges disjoint) -> 33 KB LDS not 49.7 KB.
template<int K, int N, int EPI>
__global__ __launch_bounds__(256) void gemm16(
    const f16* __restrict__ A, const f16* __restrict__ BT,
    const float* __restrict__ bias,
    float* __restrict__ outF, f16* __restrict__ outH,
    const f16* __restrict__ resid, int row_off) {
  __shared__ __align__(16) char smem[(EPI == 3) ? 64 * 129 * 4 : 16384];
  f16* As = (f16*)smem;
  f16* Bs = (f16*)(smem + 8192);
  float* tT = (float*)smem;   // EPI=3 only, used after K-loop
  int tid = threadIdx.x;
  int w = tid >> 6, lane = tid & 63;
  int wr = w >> 1, wc = w & 1;
  int r0 = blockIdx.y * 128;
  int n0 = blockIdx.x * 128;

  f32x4 acc[4][4] = {};

  for (int k0 = 0; k0 < K; k0 += 32) {
#pragma unroll
    for (int i = 0; i < 2; ++i) {
      int e = i * 256 + tid;
      int row = e >> 2, t = e & 3;
      int cb = t ^ ((row >> 1) & 3);
      gload_lds16(A + (size_t)(r0 + row) * K + k0 + cb * 8,
                  &As[(i * 4 + w) * 512]);
    }
#pragma unroll
    for (int i = 0; i < 2; ++i) {
      int e = i * 256 + tid;
      int row = e >> 2, t = e & 3;
      int cb = t ^ ((row >> 1) & 3);
      gload_lds16(BT + (size_t)(n0 + row) * K + k0 + cb * 8,
                  &Bs[(i * 4 + w) * 512]);
    }
    __syncthreads();

    f16x8 af[4], bf[4];
#pragma unroll
    for (int m = 0; m < 4; ++m) {
      int ar = wr * 64 + m * 16 + (lane & 15);
      int sl = (lane >> 4) ^ ((ar >> 1) & 3);
      af[m] = *(const f16x8*)&As[ar * 32 + sl * 8];
    }
#pragma unroll
    for (int n = 0; n < 4; ++n) {
      int br = wc * 64 + n * 16 + (lane & 15);
      int sl = (lane >> 4) ^ ((br >> 1) & 3);
      bf[n] = *(const f16x8*)&Bs[br * 32 + sl * 8];
    }
#pragma unroll
    for (int m = 0; m < 4; ++m)
#pragma unroll
      for (int n = 0; n < 4; ++n)
        acc[m][n] = __builtin_amdgcn_mfma_f32_16x16x32_f16(af[m], bf[n], acc[m][n], 0, 0, 0);
    __syncthreads();
  }

  if constexpr (EPI != 3) {
#pragma unroll
    for (int m = 0; m < 4; ++m) {
#pragma unroll
      for (int n = 0; n < 4; ++n) {
        int gcol = n0 + wc * 64 + n * 16 + (lane & 15);
        float bb = bias[gcol];
#pragma unroll
        for (int j = 0; j < 4; ++j) {
          int grow = r0 + wr * 64 + m * 16 + ((lane >> 4) << 2) + j;
          float v = acc[m][n][j] + bb;
          if constexpr (EPI == 0) {
            outH[(size_t)grow * N + gcol] = (f16)v;
          } else {
            float gl = 0.5f * v * (1.0f + erff(v * 0.70710678118654752f));
            outH[(size_t)grow * N + gcol] = (f16)gl;
          }
        }
      }
    }
  } else {
    for (int p = 0; p < 2; ++p) {
      if (wr == p) {
#pragma unroll
        for (int m = 0; m < 4; ++m) {
          int lr = m * 16 + ((lane >> 4) << 2);
#pragma unroll
          for (int n = 0; n < 4; ++n) {
            int lc = wc * 64 + n * 16 + (lane & 15);
            int gcol = n0 + lc;
            float bb = bias[gcol];
#pragma unroll
            for (int j = 0; j < 4; ++j) {
              int grow = row_off + r0 + p * 64 + lr + j;
              tT[(lr + j) * 129 + lc] =
                  acc[m][n][j] + bb + (float)resid[(size_t)grow * 512 + gcol];
            }
          }
        }
      }
      __syncthreads();
#pragma unroll
      for (int it = 0; it < 8; ++it) {
        int idx = it * 256 + tid;
        int col = idx >> 4;
        int r4 = idx & 15;
        int grow0 = row_off + r0 + p * 64 + r4 * 4;
        int b = grow0 / L_;
        int l = grow0 - b * L_;
        float4 o = make_float4(tT[(r4 * 4 + 0) * 129 + col],
                               tT[(r4 * 4 + 1) * 129 + col],
                               tT[(r4 * 4 + 2) * 129 + col],
                               tT[(r4 * 4 + 3) * 129 + col]);
        *(float4*)&outF[((size_t)b * 512 + n0 + col) * L_ + l] = o;
      }
      __syncthreads();
    }
  }
}

// ---------------------------------------------------------------------------
// Window attention v3b (unchanged from round 5): registers for scores+softmax,
// PV in two 16-wide halves. No min-waves clamp (round-4 spill lesson).
#define PST 776
__global__ __launch_bounds__(256) void attn_kernel(const f16* __restrict__ qkv,
                                                   const float* __restrict__ rel,
                                                   f16* __restrict__ outp) {
  __shared__ f16 qc[T_][PST];     // 38800 B
  __shared__ f16 relL[81 * 8];
  int tid = threadIdx.x;
  int bn = blockIdx.x;
  int b = bn >> 6, n = bn & 63;
  int u = n >> 3, v = n & 7;

  for (int e = tid; e < 648; e += 256) relL[e] = (f16)rel[e];

  for (int e = tid; e < T_ * 96; e += 256) {
    int t = e / 96;
    int g = e - t * 96;
    int i = t / 5, j = t - i * 5;
    int l = (u * 5 + i) * 40 + v * 5 + j;
    f16x8 val = *(const f16x8*)&qkv[(size_t)(b * L_ + l) * 768 + g * 8];
    int which = g >> 5;
    int d = g & 31;
    int base = which * 256 + d;
#pragma unroll
    for (int h = 0; h < 8; ++h)
      qc[t][base + h * 32] = val[h];
  }
  __syncthreads();

  int h = tid >> 5, t = tid & 31;
  if (t < T_) {
    int i1 = t / 5, j1 = t - i1 * 5;
    int par1 = (u + v + i1 + j1) & 1;
    const f16* qp = &qc[t][h * 32];
    f16x8 q0 = *(const f16x8*)(qp + 0);
    f16x8 q1 = *(const f16x8*)(qp + 8);
    f16x8 q2 = *(const f16x8*)(qp + 16);
    f16x8 q3 = *(const f16x8*)(qp + 24);

    float p[T_];
    float mx = -1e30f;
#pragma unroll
    for (int s = 0; s < T_; ++s) {
      int i2 = s / 5, j2 = s - i2 * 5;
      const f16* kp = &qc[s][256 + h * 32];
      f16x8 k0 = *(const f16x8*)(kp + 0);
      f16x8 k1 = *(const f16x8*)(kp + 8);
      f16x8 k2 = *(const f16x8*)(kp + 16);
      f16x8 k3 = *(const f16x8*)(kp + 24);
      float d0 = 0.f, d1 = 0.f;
      d0 = dot8(q0, k0, d0);
      d1 = dot8(q1, k1, d1);
      d0 = dot8(q2, k2, d0);
      d1 = dot8(q3, k3, d1);
      float bias = (float)relL[((i1 - i2 + 4) * 9 + (j1 - j2 + 4)) * 8 + h];
      int par2 = (u + v + i2 + j2) & 1;
      float sc = (d0 + d1) * QSCALE + bias + ((par1 & par2) ? 0.0f : -100.0f);
      p[s] = sc;
      mx = fmaxf(mx, sc);
    }
    float sum = 0.f;
#pragma unroll
    for (int s = 0; s < T_; ++s) {
      float e = __expf(p[s] - mx);
      p[s] = e;
      sum += e;
    }
    float inv = 1.0f / sum;
#pragma unroll
    for (int s = 0; s < T_; ++s) p[s] *= inv;

    int l = (u * 5 + i1) * 40 + v * 5 + j1;
    f16* op = &outp[(size_t)(b * L_ + l) * 256 + h * 32];

#pragma unroll
    for (int half = 0; half < 2; ++half) {
      float acc[16] = {};
#pragma unroll
      for (int s = 0; s < T_; ++s) {
        const f16* vp = &qc[s][512 + h * 32 + half * 16];
        f16x8 v0 = *(const f16x8*)(vp + 0);
        f16x8 v1 = *(const f16x8*)(vp + 8);
        float ps = p[s];
#pragma unroll
        for (int z = 0; z < 8; ++z) {
          acc[z]     += ps * (float)v0[z];
          acc[8 + z] += ps * (float)v1[z];
        }
      }
#pragma unroll
      for (int z8 = 0; z8 < 2; ++z8) {
        f16x8 ov;
#pragma unroll
        for (int z = 0; z < 8; ++z) ov[z] = (f16)acc[z8 * 8 + z];
        *(f16x8*)(op + half * 16 + z8 * 8) = ov;
      }
    }
  }
}

// ---------------------------------------------------------------------------
// LN2 fused: yln(ROWS,512) f16 = LN(y_h)*g+b, y_h f16 read once
__global__ __launch_bounds__(256) void ln2_fused(const f16* __restrict__ y,
    const float* __restrict__ g, const float* __restrict__ be,
    f16* __restrict__ yln) {
  int wv = threadIdx.x >> 6, lane = threadIdx.x & 63;
  int row = blockIdx.x * 4 + wv;
  const f16x8* yp = (const f16x8*)(y + (size_t)row * 512);
  f16x8 h0 = yp[lane];
  float v[8];
  float s = 0.f, s2 = 0.f;
#pragma unroll
  for (int z = 0; z < 8; ++z) {
    v[z] = (float)h0[z];
    s += v[z]; s2 += v[z] * v[z];
  }
#pragma unroll
  for (int o = 32; o; o >>= 1) { s += __shfl_xor(s, o); s2 += __shfl_xor(s2, o); }
  float m = s * (1.0f / 512.0f);
  float rr = rsqrtf(s2 * (1.0f / 512.0f) - m * m + 1e-5f);
  float4 g0 = ((const float4*)g)[lane * 2], g1 = ((const float4*)g)[lane * 2 + 1];
  float4 b0 = ((const float4*)be)[lane * 2], b1 = ((const float4*)be)[lane * 2 + 1];
  float gg[8] = {g0.x, g0.y, g0.z, g0.w, g1.x, g1.y, g1.z, g1.w};
  float bb[8] = {b0.x, b0.y, b0.z, b0.w, b1.x, b1.y, b1.z, b1.w};
  f16x8 o8;
#pragma unroll
  for (int z = 0; z < 8; ++z)
    o8[z] = (f16)((v[z] - m) * rr * gg[z] + bb[z]);
  *(f16x8*)&yln[(size_t)row * 512 + lane * 8] = o8;
}

// ---------------------------------------------------------------------------
extern "C" void kernel_launch(void* const* d_in, const int* in_sizes, int n_in,
                              void* d_out, int out_size, void* d_ws, size_t ws_size,
                              hipStream_t stream) {
  const float* x      = (const float*)d_in[0];
  const float* qkv_w  = (const float*)d_in[1];
  const float* qkv_b  = (const float*)d_in[2];
  const float* rel    = (const float*)d_in[3];
  const float* proj_w = (const float*)d_in[4];
  const float* proj_b = (const float*)d_in[5];
  const float* w1     = (const float*)d_in[6];
  const float* b1     = (const float*)d_in[7];
  const float* w2     = (const float*)d_in[8];
  const float* b2     = (const float*)d_in[9];
  const float* g1     = (const float*)d_in[10];
  const float* be1    = (const float*)d_in[11];
  const float* g2     = (const float*)d_in[12];
  const float* be2    = (const float*)d_in[13];
  float* out = (float*)d_out;

  // ws layout (bytes):
  //   0        : (reserved) 1,638,400
  //   1638400  : f16 weights qkv_wT, proj_wT, w1T, w2T
  //   4390912  : P0 (157MB): qkv_h f16 -> later y_h f16 (105MB, overlay)
  //   +P0      : P1 (105MB): xs_h(52.4)|att_h(52.4) -> later yln f16 (105MB)
  //   +P1      : P2 (210MB): hid f16 (full) or 52.4MB chunk
  char* w8 = (char*)d_ws;
  f16* qkv_wT  = (f16*)(w8 + 1638400);
  f16* proj_wT = qkv_wT + 768 * 256;
  f16* w1T     = proj_wT + 512 * 256;
  f16* w2T     = w1T + 1024 * 512;
  char* P0 = w8 + 4390912;
  f16* qkv_h = (f16*)P0;
  f16* y_h   = (f16*)P0;                      // overlays qkv_h (dead after attn)
  char* P1 = P0 + (size_t)ROWS * 768 * 2;
  f16* xs_h  = (f16*)P1;
  f16* att_h = (f16*)(P1 + (size_t)ROWS * 256 * 2);
  f16* yln   = (f16*)P1;                      // overlays xs/att (dead after proj)
  char* P2 = P1 + (size_t)ROWS * 512 * 2;
  f16* hid = (f16*)P2;

  size_t need_full = 4390912 + (size_t)ROWS * 768 * 2 + (size_t)ROWS * 512 * 2
                   + (size_t)ROWS * 1024 * 2;
  bool full = ws_size >= need_full;

  wtrans<<<dim3(768 / 64, 256 / 64), 256, 0, stream>>>(qkv_w, qkv_wT, 256, 768);
  wtrans<<<dim3(512 / 64, 256 / 64), 256, 0, stream>>>(proj_w, proj_wT, 256, 512);
  wtrans<<<dim3(1024 / 64, 512 / 64), 256, 0, stream>>>(w1, w1T, 512, 1024);
  wtrans<<<dim3(512 / 64, 1024 / 64), 256, 0, stream>>>(w2, w2T, 1024, 512);

  ln1_fused<<<ROWS / 64, 256, 0, stream>>>(x, g1, be1, xs_h);

  // grid: x = column-block (fast), y = row-block -> A-panel L3 reuse
  gemm16<256, 768, 0><<<dim3(6, ROWS / 128), 256, 0, stream>>>(
      xs_h, qkv_wT, qkv_b, nullptr, qkv_h, nullptr, 0);

  attn_kernel<<<B_ * 64, 256, 0, stream>>>(qkv_h, rel, att_h);

  gemm16<256, 512, 0><<<dim3(4, ROWS / 128), 256, 0, stream>>>(
      att_h, proj_wT, proj_b, nullptr, y_h, nullptr, 0);

  ln2_fused<<<ROWS / 4, 256, 0, stream>>>(y_h, g2, be2, yln);

  if (full) {
    gemm16<512, 1024, 2><<<dim3(8, ROWS / 128), 256, 0, stream>>>(
        yln, w1T, b1, nullptr, hid, nullptr, 0);
    gemm16<1024, 512, 3><<<dim3(4, ROWS / 128), 256, 0, stream>>>(
        hid, w2T, b2, out, nullptr, y_h, 0);
  } else {
    const int CHUNK = ROWS / 4;  // 25600 rows
    for (int c = 0; c < 4; ++c) {
      int off = c * CHUNK;
      gemm16<512, 1024, 2><<<dim3(8, CHUNK / 128), 256, 0, stream>>>(
          yln + (size_t)off * 512, w1T, b1, nullptr, hid, nullptr, 0);
      gemm16<1024, 512, 3><<<dim3(4, CHUNK / 128), 256, 0, stream>>>(
          hid, w2T, b2, out, nullptr, y_h, off);
    }
  }
  (void)in_sizes; (void)n_in; (void)out_size;
}

// Round 7
// 745.236 us; speedup vs baseline: 1.7873x; 1.0507x over previous
//
#include <hip/hip_runtime.h>
#include <math.h>

// Problem constants
#define B_   64
#define C_   256
#define L_   1600          // H*W = 40*40
#define T_   25            // tokens per window (5x5)
#define ROWS (B_*L_)       // 102400
#define QSCALE 0.17677669529663687f   // 1/sqrt(32)

typedef _Float16 f16;
typedef f16 f16x8 __attribute__((ext_vector_type(8)));
typedef f16 f16x4 __attribute__((ext_vector_type(4)));
typedef f16 f16x2 __attribute__((ext_vector_type(2)));
typedef float f32x4 __attribute__((ext_vector_type(4)));

__device__ __forceinline__ void gload_lds16(const void* g, void* l) {
  __builtin_amdgcn_global_load_lds(
      (const __attribute__((address_space(1))) unsigned int*)g,
      (__attribute__((address_space(3))) unsigned int*)l, 16, 0, 0);
}

__device__ __forceinline__ float dot8(f16x8 a, f16x8 b, float acc) {
  union U { f16x8 v; f16x2 p[4]; };
  U ua; ua.v = a;
  U ub; ub.v = b;
#pragma unroll
  for (int i = 0; i < 4; ++i)
    acc = __builtin_amdgcn_fdot2(ua.p[i], ub.p[i], acc, false);
  return acc;
}

// ---------------------------------------------------------------------------
// Weight convert+transpose (tiled, coalesced): o(N,K) f16 = w(K,N)^T
__global__ __launch_bounds__(256) void wtrans(const float* __restrict__ w,
                                              f16* __restrict__ o, int K, int N) {
  __shared__ f16 tile[64][72];
  int tid = threadIdx.x;
  int n0 = blockIdx.x * 64, k0 = blockIdx.y * 64;
  int nn = tid & 63, kq = tid >> 6;
#pragma unroll
  for (int i = 0; i < 16; ++i) {
    int k = kq * 16 + i;
    tile[nn][k] = (f16)w[(size_t)(k0 + k) * N + n0 + nn];
  }
  __syncthreads();
#pragma unroll
  for (int jj = 0; jj < 2; ++jj) {
    int e = jj * 256 + tid;
    int nr = e >> 3, kb = e & 7;
    *(f16x8*)&o[(size_t)(n0 + nr) * K + k0 + kb * 8] = *(const f16x8*)&tile[nr][kb * 8];
  }
}

// ---------------------------------------------------------------------------
// LN1 fused (stats + apply + transpose): xs(ROWS,256) f16 from x(B,C,L), x read once
__global__ __launch_bounds__(256) void ln1_fused(const float* __restrict__ x,
    const float* __restrict__ g, const float* __restrict__ be,
    f16* __restrict__ xs) {
  __shared__ float t32[256][65];
  __shared__ float gL[256], beL[256];
  int tid = threadIdx.x;
  gL[tid] = g[tid]; beL[tid] = be[tid];
  int r0 = blockIdx.x * 64;
  int w = tid >> 6, rl = tid & 63;
  int grow = r0 + rl;
  int b = grow / L_, l = grow - b * L_;
  const float* xb = x + (size_t)b * (C_ * L_) + l;
#pragma unroll
  for (int i = 0; i < 64; ++i) {
    int c = w + i * 4;
    t32[c][rl] = xb[(size_t)c * L_];
  }
  __syncthreads();
  int row = tid >> 2, q = tid & 3;
  float s = 0.f, s2 = 0.f;
#pragma unroll
  for (int i = 0; i < 64; ++i) {
    float vv = t32[q * 64 + i][row];
    s += vv; s2 += vv * vv;
  }
  s += __shfl_xor(s, 1); s2 += __shfl_xor(s2, 1);
  s += __shfl_xor(s, 2); s2 += __shfl_xor(s2, 2);
  float m = s * (1.0f / 256.0f);
  float rr = rsqrtf(s2 * (1.0f / 256.0f) - m * m + 1e-5f);
  f16* orow = &xs[(size_t)(r0 + row) * 256 + q * 64];
#pragma unroll
  for (int z8 = 0; z8 < 8; ++z8) {
    f16x8 ov;
#pragma unroll
    for (int z = 0; z < 8; ++z) {
      int c = q * 64 + z8 * 8 + z;
      ov[z] = (f16)((t32[c][row] - m) * rr * gL[c] + beL[c]);
    }
    *(f16x8*)(orow + z8 * 8) = ov;
  }
}

// ---------------------------------------------------------------------------
// MFMA GEMM v3: 512 threads, 8 waves (2x4), wave tile 64x32 -> acc = 32 AGPR.
// 1-D grid with XCD-affinity swizzle: xcd = bid&7 gets contiguous chunk of
// row-panels; the NCB column-sharers of one A-panel are consecutive on the
// SAME XCD -> A-panel L2 reuse. nrp8 = (M/128)/8.
// EPI: 0 = +bias -> f16 out ; 2 = gelu(+bias) -> f16 out
//      3 = +bias +resid(f16) -> transposed (B,512,L) f32 out
template<int K, int N, int EPI, int NCB>
__global__ __launch_bounds__(512) void gemm16(
    const f16* __restrict__ A, const f16* __restrict__ BT,
    const float* __restrict__ bias,
    float* __restrict__ outF, f16* __restrict__ outH,
    const f16* __restrict__ resid, int row_off, int nrp8) {
  __shared__ __align__(16) char smem[(EPI == 3) ? 64 * 129 * 4 : 16384];
  f16* As = (f16*)smem;
  f16* Bs = (f16*)(smem + 8192);
  float* tT = (float*)smem;   // EPI=3 only, used after K-loop
  int tid = threadIdx.x;
  int w = tid >> 6, lane = tid & 63;
  int wr = w >> 2, wc = w & 3;            // 2 x 4 wave grid
  int bid = blockIdx.x;
  int xcd = bid & 7, j1d = bid >> 3;
  int member = j1d % NCB, grp = j1d / NCB;
  int r0 = (xcd * nrp8 + grp) * 128;
  int n0 = member * 128;

  f32x4 acc[4][2] = {};
  int srow = tid >> 2, st = tid & 3;
  int scb = st ^ ((srow >> 1) & 3);       // inverse-swizzled source colblock

  for (int k0 = 0; k0 < K; k0 += 32) {
    gload_lds16(A + (size_t)(r0 + srow) * K + k0 + scb * 8, &As[w * 512]);
    gload_lds16(BT + (size_t)(n0 + srow) * K + k0 + scb * 8, &Bs[w * 512]);
    __syncthreads();

    f16x8 af[4], bf[2];
#pragma unroll
    for (int m = 0; m < 4; ++m) {
      int ar = wr * 64 + m * 16 + (lane & 15);
      int sl = (lane >> 4) ^ ((ar >> 1) & 3);   // swizzled read slot
      af[m] = *(const f16x8*)&As[ar * 32 + sl * 8];
    }
#pragma unroll
    for (int n = 0; n < 2; ++n) {
      int br = wc * 32 + n * 16 + (lane & 15);
      int sl = (lane >> 4) ^ ((br >> 1) & 3);
      bf[n] = *(const f16x8*)&Bs[br * 32 + sl * 8];
    }
#pragma unroll
    for (int m = 0; m < 4; ++m)
#pragma unroll
      for (int n = 0; n < 2; ++n)
        acc[m][n] = __builtin_amdgcn_mfma_f32_16x16x32_f16(af[m], bf[n], acc[m][n], 0, 0, 0);
    __syncthreads();
  }

  if constexpr (EPI != 3) {
#pragma unroll
    for (int m = 0; m < 4; ++m) {
#pragma unroll
      for (int n = 0; n < 2; ++n) {
        int gcol = n0 + wc * 32 + n * 16 + (lane & 15);
        float bb = bias[gcol];
#pragma unroll
        for (int j2 = 0; j2 < 4; ++j2) {
          int grow = r0 + wr * 64 + m * 16 + ((lane >> 4) << 2) + j2;
          float vv = acc[m][n][j2] + bb;
          if constexpr (EPI == 0) {
            outH[(size_t)grow * N + gcol] = (f16)vv;
          } else {
            float gl = 0.5f * vv * (1.0f + erff(vv * 0.70710678118654752f));
            outH[(size_t)grow * N + gcol] = (f16)gl;
          }
        }
      }
    }
  } else {
    for (int p = 0; p < 2; ++p) {
      if (wr == p) {
#pragma unroll
        for (int m = 0; m < 4; ++m) {
          int lr = m * 16 + ((lane >> 4) << 2);
#pragma unroll
          for (int n = 0; n < 2; ++n) {
            int lc = wc * 32 + n * 16 + (lane & 15);
            int gcol = n0 + lc;
            float bb = bias[gcol];
#pragma unroll
            for (int j2 = 0; j2 < 4; ++j2) {
              int grow = row_off + r0 + p * 64 + lr + j2;
              tT[(lr + j2) * 129 + lc] =
                  acc[m][n][j2] + bb + (float)resid[(size_t)grow * 512 + gcol];
            }
          }
        }
      }
      __syncthreads();
#pragma unroll
      for (int it = 0; it < 4; ++it) {
        int idx = it * 512 + tid;
        int col = idx >> 4;
        int r4 = idx & 15;
        int grow0 = row_off + r0 + p * 64 + r4 * 4;
        int b = grow0 / L_;
        int l = grow0 - b * L_;
        float4 o = make_float4(tT[(r4 * 4 + 0) * 129 + col],
                               tT[(r4 * 4 + 1) * 129 + col],
                               tT[(r4 * 4 + 2) * 129 + col],
                               tT[(r4 * 4 + 3) * 129 + col]);
        *(float4*)&outF[((size_t)b * 512 + n0 + col) * L_ + l] = o;
      }
      __syncthreads();
    }
  }
}

// ---------------------------------------------------------------------------
// Window attention v3b (unchanged): registers for scores+softmax, PV halves.
#define PST 776
__global__ __launch_bounds__(256) void attn_kernel(const f16* __restrict__ qkv,
                                                   const float* __restrict__ rel,
                                                   f16* __restrict__ outp) {
  __shared__ f16 qc[T_][PST];     // 38800 B
  __shared__ f16 relL[81 * 8];
  int tid = threadIdx.x;
  int bn = blockIdx.x;
  int b = bn >> 6, n = bn & 63;
  int u = n >> 3, v = n & 7;

  for (int e = tid; e < 648; e += 256) relL[e] = (f16)rel[e];

  for (int e = tid; e < T_ * 96; e += 256) {
    int t = e / 96;
    int g = e - t * 96;
    int i = t / 5, j = t - i * 5;
    int l = (u * 5 + i) * 40 + v * 5 + j;
    f16x8 val = *(const f16x8*)&qkv[(size_t)(b * L_ + l) * 768 + g * 8];
    int which = g >> 5;
    int d = g & 31;
    int base = which * 256 + d;
#pragma unroll
    for (int h = 0; h < 8; ++h)
      qc[t][base + h * 32] = val[h];
  }
  __syncthreads();

  int h = tid >> 5, t = tid & 31;
  if (t < T_) {
    int i1 = t / 5, j1 = t - i1 * 5;
    int par1 = (u + v + i1 + j1) & 1;
    const f16* qp = &qc[t][h * 32];
    f16x8 q0 = *(const f16x8*)(qp + 0);
    f16x8 q1 = *(const f16x8*)(qp + 8);
    f16x8 q2 = *(const f16x8*)(qp + 16);
    f16x8 q3 = *(const f16x8*)(qp + 24);

    float p[T_];
    float mx = -1e30f;
#pragma unroll
    for (int s = 0; s < T_; ++s) {
      int i2 = s / 5, j2 = s - i2 * 5;
      const f16* kp = &qc[s][256 + h * 32];
      f16x8 k0 = *(const f16x8*)(kp + 0);
      f16x8 k1 = *(const f16x8*)(kp + 8);
      f16x8 k2 = *(const f16x8*)(kp + 16);
      f16x8 k3 = *(const f16x8*)(kp + 24);
      float d0 = 0.f, d1 = 0.f;
      d0 = dot8(q0, k0, d0);
      d1 = dot8(q1, k1, d1);
      d0 = dot8(q2, k2, d0);
      d1 = dot8(q3, k3, d1);
      float bias = (float)relL[((i1 - i2 + 4) * 9 + (j1 - j2 + 4)) * 8 + h];
      int par2 = (u + v + i2 + j2) & 1;
      float sc = (d0 + d1) * QSCALE + bias + ((par1 & par2) ? 0.0f : -100.0f);
      p[s] = sc;
      mx = fmaxf(mx, sc);
    }
    float sum = 0.f;
#pragma unroll
    for (int s = 0; s < T_; ++s) {
      float e = __expf(p[s] - mx);
      p[s] = e;
      sum += e;
    }
    float inv = 1.0f / sum;
#pragma unroll
    for (int s = 0; s < T_; ++s) p[s] *= inv;

    int l = (u * 5 + i1) * 40 + v * 5 + j1;
    f16* op = &outp[(size_t)(b * L_ + l) * 256 + h * 32];

#pragma unroll
    for (int half = 0; half < 2; ++half) {
      float acc[16] = {};
#pragma unroll
      for (int s = 0; s < T_; ++s) {
        const f16* vp = &qc[s][512 + h * 32 + half * 16];
        f16x8 v0 = *(const f16x8*)(vp + 0);
        f16x8 v1 = *(const f16x8*)(vp + 8);
        float ps = p[s];
#pragma unroll
        for (int z = 0; z < 8; ++z) {
          acc[z]     += ps * (float)v0[z];
          acc[8 + z] += ps * (float)v1[z];
        }
      }
#pragma unroll
      for (int z8 = 0; z8 < 2; ++z8) {
        f16x8 ov;
#pragma unroll
        for (int z = 0; z < 8; ++z) ov[z] = (f16)acc[z8 * 8 + z];
        *(f16x8*)(op + half * 16 + z8 * 8) = ov;
      }
    }
  }
}

// ---------------------------------------------------------------------------
// LN2 fused: yln(ROWS,512) f16 = LN(y_h)*g+b, y_h f16 read once
__global__ __launch_bounds__(256) void ln2_fused(const f16* __restrict__ y,
    const float* __restrict__ g, const float* __restrict__ be,
    f16* __restrict__ yln) {
  int wv = threadIdx.x >> 6, lane = threadIdx.x & 63;
  int row = blockIdx.x * 4 + wv;
  const f16x8* yp = (const f16x8*)(y + (size_t)row * 512);
  f16x8 h0 = yp[lane];
  float v[8];
  float s = 0.f, s2 = 0.f;
#pragma unroll
  for (int z = 0; z < 8; ++z) {
    v[z] = (float)h0[z];
    s += v[z]; s2 += v[z] * v[z];
  }
#pragma unroll
  for (int o = 32; o; o >>= 1) { s += __shfl_xor(s, o); s2 += __shfl_xor(s2, o); }
  float m = s * (1.0f / 512.0f);
  float rr = rsqrtf(s2 * (1.0f / 512.0f) - m * m + 1e-5f);
  float4 g0 = ((const float4*)g)[lane * 2], g1 = ((const float4*)g)[lane * 2 + 1];
  float4 b0 = ((const float4*)be)[lane * 2], b1 = ((const float4*)be)[lane * 2 + 1];
  float gg[8] = {g0.x, g0.y, g0.z, g0.w, g1.x, g1.y, g1.z, g1.w};
  float bb[8] = {b0.x, b0.y, b0.z, b0.w, b1.x, b1.y, b1.z, b1.w};
  f16x8 o8;
#pragma unroll
  for (int z = 0; z < 8; ++z)
    o8[z] = (f16)((v[z] - m) * rr * gg[z] + bb[z]);
  *(f16x8*)&yln[(size_t)row * 512 + lane * 8] = o8;
}

// ---------------------------------------------------------------------------
extern "C" void kernel_launch(void* const* d_in, const int* in_sizes, int n_in,
                              void* d_out, int out_size, void* d_ws, size_t ws_size,
                              hipStream_t stream) {
  const float* x      = (const float*)d_in[0];
  const float* qkv_w  = (const float*)d_in[1];
  const float* qkv_b  = (const float*)d_in[2];
  const float* rel    = (const float*)d_in[3];
  const float* proj_w = (const float*)d_in[4];
  const float* proj_b = (const float*)d_in[5];
  const float* w1     = (const float*)d_in[6];
  const float* b1     = (const float*)d_in[7];
  const float* w2     = (const float*)d_in[8];
  const float* b2     = (const float*)d_in[9];
  const float* g1     = (const float*)d_in[10];
  const float* be1    = (const float*)d_in[11];
  const float* g2     = (const float*)d_in[12];
  const float* be2    = (const float*)d_in[13];
  float* out = (float*)d_out;

  // ws layout (bytes): as round 6.
  char* w8 = (char*)d_ws;
  f16* qkv_wT  = (f16*)(w8 + 1638400);
  f16* proj_wT = qkv_wT + 768 * 256;
  f16* w1T     = proj_wT + 512 * 256;
  f16* w2T     = w1T + 1024 * 512;
  char* P0 = w8 + 4390912;
  f16* qkv_h = (f16*)P0;
  f16* y_h   = (f16*)P0;                      // overlays qkv_h (dead after attn)
  char* P1 = P0 + (size_t)ROWS * 768 * 2;
  f16* xs_h  = (f16*)P1;
  f16* att_h = (f16*)(P1 + (size_t)ROWS * 256 * 2);
  f16* yln   = (f16*)P1;                      // overlays xs/att (dead after proj)
  char* P2 = P1 + (size_t)ROWS * 512 * 2;
  f16* hid = (f16*)P2;

  size_t need_full = 4390912 + (size_t)ROWS * 768 * 2 + (size_t)ROWS * 512 * 2
                   + (size_t)ROWS * 1024 * 2;
  bool full = ws_size >= need_full;

  wtrans<<<dim3(768 / 64, 256 / 64), 256, 0, stream>>>(qkv_w, qkv_wT, 256, 768);
  wtrans<<<dim3(512 / 64, 256 / 64), 256, 0, stream>>>(proj_w, proj_wT, 256, 512);
  wtrans<<<dim3(1024 / 64, 512 / 64), 256, 0, stream>>>(w1, w1T, 512, 1024);
  wtrans<<<dim3(512 / 64, 1024 / 64), 256, 0, stream>>>(w2, w2T, 1024, 512);

  ln1_fused<<<ROWS / 64, 256, 0, stream>>>(x, g1, be1, xs_h);

  // 1-D swizzled grids: nrp8 = (M/128)/8
  gemm16<256, 768, 0, 6><<<6 * (ROWS / 128), 512, 0, stream>>>(
      xs_h, qkv_wT, qkv_b, nullptr, qkv_h, nullptr, 0, (ROWS / 128) / 8);

  attn_kernel<<<B_ * 64, 256, 0, stream>>>(qkv_h, rel, att_h);

  gemm16<256, 512, 0, 4><<<4 * (ROWS / 128), 512, 0, stream>>>(
      att_h, proj_wT, proj_b, nullptr, y_h, nullptr, 0, (ROWS / 128) / 8);

  ln2_fused<<<ROWS / 4, 256, 0, stream>>>(y_h, g2, be2, yln);

  if (full) {
    gemm16<512, 1024, 2, 8><<<8 * (ROWS / 128), 512, 0, stream>>>(
        yln, w1T, b1, nullptr, hid, nullptr, 0, (ROWS / 128) / 8);
    gemm16<1024, 512, 3, 4><<<4 * (ROWS / 128), 512, 0, stream>>>(
        hid, w2T, b2, out, nullptr, y_h, 0, (ROWS / 128) / 8);
  } else {
    const int CHUNK = ROWS / 4;  // 25600 rows, 200 panels -> nrp8 = 25
    for (int c = 0; c < 4; ++c) {
      int off = c * CHUNK;
      gemm16<512, 1024, 2, 8><<<8 * (CHUNK / 128), 512, 0, stream>>>(
          yln + (size_t)off * 512, w1T, b1, nullptr, hid, nullptr, off, (CHUNK / 128) / 8);
      gemm16<1024, 512, 3, 4><<<4 * (CHUNK / 128), 512, 0, stream>>>(
          hid, w2T, b2, out, nullptr, y_h, off, (CHUNK / 128) / 8);
    }
  }
  (void)in_sizes; (void)n_in; (void)out_size;
}